// Round 3
// baseline (1248.855 us; speedup 1.0000x reference)
//
#include <hip/hip_runtime.h>
#include <hip/hip_bf16.h>
#include <math.h>

typedef __bf16 bf16x8 __attribute__((ext_vector_type(8)));
typedef float f32x4 __attribute__((ext_vector_type(4)));
typedef unsigned long long u64;

#define LDS_AS __attribute__((address_space(3)))
#define GLB_AS __attribute__((address_space(1)))

__device__ __forceinline__ void gload16(const void* g, void* l) {
  __builtin_amdgcn_global_load_lds((const GLB_AS void*)g, (LDS_AS void*)l, 16, 0, 0);
}

__device__ __forceinline__ unsigned short f2bf(float f) {
  unsigned u = __float_as_uint(f);
  u += 0x7FFFu + ((u >> 16) & 1u);
  return (unsigned short)(u >> 16);
}
__device__ __forceinline__ float bf2f(unsigned short h) {
  return __uint_as_float(((unsigned)h) << 16);
}
__device__ __forceinline__ float gelu_t(float x) {
  float x3 = x * x * x;
  return 0.5f * x * (1.0f + tanhf(0.7978845608028654f * (x + 0.044715f * x3)));
}

// ---------------- problem constants ----------------
#define ROWS 16384    // B*S
#define DIM  1024     // D
#define NEXP 8
#define DDIM 4096
#define KCAP 2048     // ROWS/NEXP

// ---------------- workspace layout (bytes) ----------------
#define WS_NORM    0ull                      // 16384*1024*2 = 33554432  (bf16 norm_x)
#define WS_G1      33554432ull               // 33554432                 (bf16 gelu(cp fc1))
#define WS_YIN     67108864ull               // 33554432                 (bf16 gathered rows, [n][2048][1024])
#define WS_FCBUF   100663296ull              // 33554432                 (bf16 4-expert weight buffer)
#define WS_H1      134217728ull              // 67108864                 (bf16 [z<4][2048][4096])
#define WS_W1B     201326592ull              // 2097152                  (bf16 cp_W1)
#define WS_S64     203423744ull              // 16384*8*8 = 1048576      (f64 scores [n][row])
#define WS_S32     204472320ull              // 16384*8*4 = 524288       (f32 scores [n][row])
#define WS_KIDX    204996608ull              // 8*2048*4 = 65536
#define WS_MASK    205062144ull              // 16384*8 = 131072         (u8 keep mask [row][n])
#define WS_LOSS    205193216ull              // 256
#define WS_NEEDED  205193472ull

// ================= LayerNorm + gate scores =================
// one block (256 thr) per row. norm -> bf16; gate dot in f64 -> scores.
__global__ __launch_bounds__(256)
void ln_score_k(const float* __restrict__ x, const float* __restrict__ lng,
                const float* __restrict__ lnb, const float* __restrict__ gw,
                unsigned short* __restrict__ normb, float* __restrict__ s32,
                double* __restrict__ s64)
{
  const int row = blockIdx.x;
  const int t = threadIdx.x, w = t >> 6, l = t & 63;
  const float* xr = x + (size_t)row * DIM;
  float4 v = ((const float4*)xr)[t];

  __shared__ float red[4];
  __shared__ float mu_s, inv_s;
  __shared__ double pd[4][8];

  float s = v.x + v.y + v.z + v.w;
  #pragma unroll
  for (int o = 32; o; o >>= 1) s += __shfl_xor(s, o);
  if (l == 0) red[w] = s;
  __syncthreads();
  if (t == 0) mu_s = (red[0] + red[1] + red[2] + red[3]) * (1.0f / DIM);
  __syncthreads();
  const float mu = mu_s;
  float d0 = v.x - mu, d1 = v.y - mu, d2 = v.z - mu, d3 = v.w - mu;
  float s2 = d0*d0 + d1*d1 + d2*d2 + d3*d3;
  #pragma unroll
  for (int o = 32; o; o >>= 1) s2 += __shfl_xor(s2, o);
  if (l == 0) red[w] = s2;
  __syncthreads();
  if (t == 0) {
    float var = (red[0] + red[1] + red[2] + red[3]) * (1.0f / DIM);
    inv_s = 1.0f / sqrtf(var + 1e-5f);
  }
  __syncthreads();
  const float inv = inv_s;

  float4 gv = ((const float4*)lng)[t];
  float4 bv = ((const float4*)lnb)[t];
  float n0 = d0 * inv * gv.x + bv.x;
  float n1 = d1 * inv * gv.y + bv.y;
  float n2 = d2 * inv * gv.z + bv.z;
  float n3 = d3 * inv * gv.w + bv.w;

  ushort4 nb;
  nb.x = f2bf(n0); nb.y = f2bf(n1); nb.z = f2bf(n2); nb.w = f2bf(n3);
  ((ushort4*)(normb + (size_t)row * DIM))[t] = nb;

  const int c0 = t * 4;
  double p[8];
  #pragma unroll
  for (int n = 0; n < 8; ++n) {
    float4 wv = *(const float4*)(gw + n * DIM + c0);
    p[n] = (double)n0 * wv.x + (double)n1 * wv.y + (double)n2 * wv.z + (double)n3 * wv.w;
  }
  #pragma unroll
  for (int n = 0; n < 8; ++n) {
    double q = p[n];
    #pragma unroll
    for (int o = 32; o; o >>= 1) q += __shfl_xor(q, o);
    if (l == 0) pd[w][n] = q;
  }
  __syncthreads();
  if (t < 8) {
    double d = pd[0][t] + pd[1][t] + pd[2][t] + pd[3][t];
    double sc = (tanh(d) + 1.0) * 0.5;
    s64[(size_t)t * ROWS + row] = sc;
    s32[(size_t)t * ROWS + row] = (float)sc;
  }
}

// ================= exact top-k per expert =================
// one block (1024 thr) per expert; keys = f64 score bits (positive -> order-preserving)
__global__ __launch_bounds__(1024)
void topk_k(const double* __restrict__ s64, int* __restrict__ kidx,
            unsigned char* __restrict__ mask)
{
  __shared__ int redc[16];
  __shared__ int bci;
  __shared__ int cntr;
  const int n = blockIdx.x, t = threadIdx.x;
  const u64* keys = (const u64*)(s64 + (size_t)n * ROWS);
  u64 kk[16];
  #pragma unroll
  for (int i = 0; i < 16; ++i) kk[i] = keys[i * 1024 + t];

  auto blockSum = [&](int local) -> int {
    #pragma unroll
    for (int o = 32; o; o >>= 1) local += __shfl_xor(local, o);
    if ((t & 63) == 0) redc[t >> 6] = local;
    __syncthreads();
    if (t == 0) {
      int s = 0;
      #pragma unroll
      for (int i = 0; i < 16; ++i) s += redc[i];
      bci = s;
    }
    __syncthreads();
    return bci;
  };

  // binary search for the k-th largest key value
  u64 lo = 0, hi = ~0ull;
  while (lo < hi) {
    u64 d = hi - lo;
    u64 mid = lo + (d >> 1) + (d & 1);
    int c = 0;
    #pragma unroll
    for (int i = 0; i < 16; ++i) c += (kk[i] >= mid);
    int tot = blockSum(c);
    if (tot >= KCAP) lo = mid; else hi = mid - 1;
  }
  const u64 kv = lo;
  int cg = 0;
  #pragma unroll
  for (int i = 0; i < 16; ++i) cg += (kk[i] > kv);
  const int m = blockSum(cg);
  const int need = KCAP - m;   // >=1

  // among keys == kv, keep the `need` smallest row indices (stable-sort tiebreak)
  int lo2 = 0, hi2 = ROWS;
  while (lo2 < hi2) {
    int mid = (lo2 + hi2) >> 1;
    int c2 = 0;
    #pragma unroll
    for (int i = 0; i < 16; ++i) c2 += (kk[i] == kv && (i * 1024 + t) < mid);
    int tot = blockSum(c2);
    if (tot >= need) hi2 = mid; else lo2 = mid + 1;
  }
  const int T = lo2;

  if (t == 0) cntr = 0;
  __syncthreads();
  #pragma unroll
  for (int i = 0; i < 16; ++i) {
    int r = i * 1024 + t;
    bool keep = (kk[i] > kv) || (kk[i] == kv && r < T);
    mask[(size_t)r * NEXP + n] = keep ? 1 : 0;
    if (keep) {
      int p = atomicAdd(&cntr, 1);
      kidx[n * KCAP + p] = r;
    }
  }
}

// ================= f32 -> bf16 convert =================
__global__ void cvt_k(const float* __restrict__ src, unsigned short* __restrict__ dst, int n4)
{
  int i = blockIdx.x * blockDim.x + threadIdx.x;
  int stride = gridDim.x * blockDim.x;
  for (; i < n4; i += stride) {
    float4 v = ((const float4*)src)[i];
    ushort4 o;
    o.x = f2bf(v.x); o.y = f2bf(v.y); o.z = f2bf(v.z); o.w = f2bf(v.w);
    ((ushort4*)dst)[i] = o;
  }
}

// ================= gather selected rows =================
__global__ __launch_bounds__(256)
void gather_k(const unsigned short* __restrict__ normb, const int* __restrict__ kidx,
              unsigned short* __restrict__ yin)
{
  int b = blockIdx.x;           // = n*2048 + j
  int row = kidx[b];
  const uint2* src = (const uint2*)(normb + (size_t)row * DIM);
  uint2* dst = (uint2*)(yin + (size_t)b * DIM);
  dst[threadIdx.x] = src[threadIdx.x];
}

// ================= 128x128 bf16 B^T GEMM, 2-phase dbuf =================
// C[M,N] = A[M,K] * B[N,K]^T ;  EPI 0: gelu(acc+bias)->bf16 ; EPI 1: (acc+bias)*score -> atomicAdd scatter
template<int EPI>
__global__ __launch_bounds__(256, 2)
void gemm_bt(const unsigned short* __restrict__ A, long strideAz, int lda,
             const unsigned short* __restrict__ B, long strideBz, int ldb,
             const float* __restrict__ bias, int strideBias,
             int K,
             unsigned short* __restrict__ outb, long strideOz, int ldo,
             float* __restrict__ outf, const int* __restrict__ kidx,
             const float* __restrict__ sc32, int n0)
{
  __shared__ __align__(16) char smem[32768];   // 2 x (A 8KB + B 8KB)
  const int t = threadIdx.x;
  const int w = t >> 6, l = t & 63;
  const int z = blockIdx.z;
  const int rowBase = blockIdx.y * 128;
  const int colBase = blockIdx.x * 128;
  const unsigned short* Ab = A + (long)z * strideAz + (long)rowBase * lda;
  const unsigned short* Bb = B + (long)z * strideBz + (long)colBase * ldb;
  const int srow = t >> 2, scol = (t & 3) * 8;
  const unsigned short* ga = Ab + (long)srow * lda + scol;
  const unsigned short* gb = Bb + (long)srow * ldb + scol;
  const int ldsW = w * 1024;     // per-wave chunk base (bytes)

  const int fr = l & 15, fq = l >> 4;
  const int wr = w >> 1, wc = w & 1;
  const int aoff = (wr * 64 + fr) * 64 + fq * 16;   // bytes into A tile
  const int boff = (wc * 64 + fr) * 64 + fq * 16;   // bytes into B tile

  f32x4 acc[4][4];
  #pragma unroll
  for (int mi = 0; mi < 4; ++mi)
    #pragma unroll
    for (int ni = 0; ni < 4; ++ni)
      acc[mi][ni] = (f32x4){0.f, 0.f, 0.f, 0.f};

  auto STAGE = [&](int buf, int k0) {
    char* s = smem + buf * 16384;
    gload16(ga + k0,                s + ldsW);
    gload16(ga + (long)64 * lda + k0, s + 4096 + ldsW);
    gload16(gb + k0,                s + 8192 + ldsW);
    gload16(gb + (long)64 * ldb + k0, s + 8192 + 4096 + ldsW);
  };

  STAGE(0, 0);
  __syncthreads();            // vmcnt drained by compiler -> buf0 ready
  int cur = 0;
  for (int k0 = 0; k0 < K; k0 += 32) {
    if (k0 + 32 < K) STAGE(cur ^ 1, k0 + 32);   // prefetch flies under compute
    const char* s = smem + cur * 16384;
    bf16x8 af[4], bfr[4];
    #pragma unroll
    for (int mi = 0; mi < 4; ++mi) af[mi] = *(const bf16x8*)(s + aoff + mi * 1024);
    #pragma unroll
    for (int ni = 0; ni < 4; ++ni) bfr[ni] = *(const bf16x8*)(s + 8192 + boff + ni * 1024);
    #pragma unroll
    for (int mi = 0; mi < 4; ++mi)
      #pragma unroll
      for (int ni = 0; ni < 4; ++ni)
        acc[mi][ni] = __builtin_amdgcn_mfma_f32_16x16x32_bf16(af[mi], bfr[ni], acc[mi][ni], 0, 0, 0);
    __syncthreads();          // drains stage vmcnt + lgkm; both buffers settled
    cur ^= 1;
  }

  const int r0 = wr * 64 + fq * 4;
  const int c0 = wc * 64 + fr;
  if constexpr (EPI == 0) {
    #pragma unroll
    for (int mi = 0; mi < 4; ++mi) {
      #pragma unroll
      for (int ni = 0; ni < 4; ++ni) {
        int cg = colBase + c0 + ni * 16;
        float bv = bias[z * strideBias + cg];
        #pragma unroll
        for (int j = 0; j < 4; ++j) {
          int rg = rowBase + r0 + mi * 16 + j;
          float g = gelu_t(acc[mi][ni][j] + bv);
          outb[(long)z * strideOz + (long)rg * ldo + cg] = f2bf(g);
        }
      }
    }
  } else {
    const int n = n0 + z;
    const int* kk = kidx + n * KCAP;
    const float* ss = sc32 + (long)n * ROWS;
    #pragma unroll
    for (int mi = 0; mi < 4; ++mi) {
      #pragma unroll
      for (int j = 0; j < 4; ++j) {
        int rg = rowBase + r0 + mi * 16 + j;   // local row in [0,2048)
        int target = kk[rg];
        float sc = ss[target];
        #pragma unroll
        for (int ni = 0; ni < 4; ++ni) {
          int cg = colBase + c0 + ni * 16;
          float v = (acc[mi][ni][j] + bias[z * strideBias + cg]) * sc;
          atomicAdd(outf + (long)target * DIM + cg, v);
        }
      }
    }
  }
}

// ================= capacity logits + loss =================
// one wave per row; logits = g1 . cp_W2[n] + b2 ; loss += softplus - logit*mask
__global__ __launch_bounds__(256)
void cap_loss_k(const unsigned short* __restrict__ g1, const float* __restrict__ W2,
                const float* __restrict__ b2, const unsigned char* __restrict__ mask,
                float* __restrict__ accum)
{
  const int w = threadIdx.x >> 6, l = threadIdx.x & 63;
  const int row = blockIdx.x * 4 + w;
  const unsigned int* gr = (const unsigned int*)(g1 + (size_t)row * DIM) + l * 8;
  float gv[16];
  #pragma unroll
  for (int i = 0; i < 8; ++i) {
    unsigned u = gr[i];
    gv[2 * i]     = bf2f((unsigned short)(u & 0xffff));
    gv[2 * i + 1] = bf2f((unsigned short)(u >> 16));
  }
  float par[8];
  #pragma unroll
  for (int n = 0; n < 8; ++n) {
    const float* wp = W2 + n * DIM + l * 16;
    float s = 0.f;
    #pragma unroll
    for (int i = 0; i < 16; ++i) s += gv[i] * wp[i];
    par[n] = s;
  }
  #pragma unroll
  for (int n = 0; n < 8; ++n) {
    float p = par[n];
    #pragma unroll
    for (int o = 32; o; o >>= 1) p += __shfl_xor(p, o);
    par[n] = p;
  }
  if (l == 0) {
    float lsum = 0.f;
    #pragma unroll
    for (int n = 0; n < 8; ++n) {
      float lg = par[n] + b2[n];
      float sp = fmaxf(lg, 0.f) + log1pf(expf(-fabsf(lg)));
      lsum += sp - lg * (float)mask[(size_t)row * NEXP + n];
    }
    atomicAdd(accum, lsum * (1.0f / (ROWS * (float)NEXP)));
  }
}

__global__ void write_loss_k(const float* __restrict__ a, float* __restrict__ o, int pos)
{
  o[pos] = *a;
}

// ================= launch =================
extern "C" void kernel_launch(void* const* d_in, const int* in_sizes, int n_in,
                              void* d_out, int out_size, void* d_ws, size_t ws_size,
                              hipStream_t stream)
{
  if (ws_size < WS_NEEDED) return;  // workspace too small -> fail loudly via validation

  const float* x     = (const float*)d_in[0];
  const float* ln_g  = (const float*)d_in[1];
  const float* ln_b  = (const float*)d_in[2];
  const float* gateW = (const float*)d_in[3];
  const float* cpW1  = (const float*)d_in[4];
  const float* cpb1  = (const float*)d_in[5];
  const float* cpW2  = (const float*)d_in[6];
  const float* cpb2  = (const float*)d_in[7];
  const float* fc1s  = (const float*)d_in[8];
  const float* b1s   = (const float*)d_in[9];
  const float* fc2s  = (const float*)d_in[10];
  const float* b2s   = (const float*)d_in[11];

  char* ws = (char*)d_ws;
  unsigned short* normb = (unsigned short*)(ws + WS_NORM);
  unsigned short* g1    = (unsigned short*)(ws + WS_G1);
  unsigned short* yin   = (unsigned short*)(ws + WS_YIN);
  unsigned short* fcbuf = (unsigned short*)(ws + WS_FCBUF);
  unsigned short* h1    = (unsigned short*)(ws + WS_H1);
  unsigned short* w1b   = (unsigned short*)(ws + WS_W1B);
  double*  s64 = (double*)(ws + WS_S64);
  float*   s32 = (float*)(ws + WS_S32);
  int*     kidx = (int*)(ws + WS_KIDX);
  unsigned char* mask = (unsigned char*)(ws + WS_MASK);
  float*   loss = (float*)(ws + WS_LOSS);
  float*   out = (float*)d_out;

  // out starts as xf (scatter-add target); loss accumulator zeroed
  hipMemcpyAsync(out, x, (size_t)ROWS * DIM * sizeof(float), hipMemcpyDeviceToDevice, stream);
  hipMemsetAsync(loss, 0, sizeof(float), stream);

  ln_score_k<<<ROWS, 256, 0, stream>>>(x, ln_g, ln_b, gateW, normb, s32, s64);
  topk_k<<<NEXP, 1024, 0, stream>>>(s64, kidx, mask);

  // capacity predictor
  cvt_k<<<2048, 256, 0, stream>>>(cpW1, w1b, DIM * DIM / 4);
  gemm_bt<0><<<dim3(DIM / 128, ROWS / 128, 1), 256, 0, stream>>>(
      normb, 0, DIM, w1b, 0, DIM, cpb1, 0, DIM,
      g1, 0, DIM, nullptr, nullptr, nullptr, 0);
  cap_loss_k<<<ROWS / 4, 256, 0, stream>>>(g1, cpW2, cpb2, mask, loss);
  write_loss_k<<<1, 1, 0, stream>>>(loss, out, out_size - 1);

  // expert path
  gather_k<<<NEXP * KCAP, 256, 0, stream>>>(normb, kidx, yin);
  for (int h = 0; h < 2; ++h) {
    cvt_k<<<4096, 256, 0, stream>>>(fc1s + (size_t)h * 4 * DDIM * DIM, fcbuf, 4 * DDIM * DIM / 4);
    gemm_bt<0><<<dim3(DDIM / 128, KCAP / 128, 4), 256, 0, stream>>>(
        yin + (size_t)h * 4 * KCAP * DIM, (long)KCAP * DIM, DIM,
        fcbuf, (long)DDIM * DIM, DIM,
        b1s + h * 4 * DDIM, DDIM, DIM,
        h1, (long)KCAP * DDIM, DDIM, nullptr, nullptr, nullptr, 0);
    cvt_k<<<4096, 256, 0, stream>>>(fc2s + (size_t)h * 4 * DIM * DDIM, fcbuf, 4 * DIM * DDIM / 4);
    gemm_bt<1><<<dim3(DIM / 128, KCAP / 128, 4), 256, 0, stream>>>(
        h1, (long)KCAP * DDIM, DDIM,
        fcbuf, (long)DIM * DDIM, DDIM,
        b2s + h * 4 * DIM, DIM, DDIM,
        nullptr, 0, 0, out, kidx, s32, h * 4);
  }
}

// Round 4
// 1070.545 us; speedup vs baseline: 1.1666x; 1.1666x over previous
//
#include <hip/hip_runtime.h>
#include <hip/hip_bf16.h>
#include <math.h>

typedef __bf16 bf16x8 __attribute__((ext_vector_type(8)));
typedef float f32x4 __attribute__((ext_vector_type(4)));
typedef unsigned long long u64;

#define LDS_AS __attribute__((address_space(3)))
#define GLB_AS __attribute__((address_space(1)))

__device__ __forceinline__ void gload16(const void* g, void* l) {
  __builtin_amdgcn_global_load_lds((const GLB_AS void*)g, (LDS_AS void*)l, 16, 0, 0);
}

__device__ __forceinline__ unsigned short f2bf(float f) {
  unsigned u = __float_as_uint(f);
  u += 0x7FFFu + ((u >> 16) & 1u);
  return (unsigned short)(u >> 16);
}
__device__ __forceinline__ float bf2f(unsigned short h) {
  return __uint_as_float(((unsigned)h) << 16);
}
__device__ __forceinline__ float gelu_t(float x) {
  float x3 = x * x * x;
  return 0.5f * x * (1.0f + tanhf(0.7978845608028654f * (x + 0.044715f * x3)));
}

// ---------------- problem constants ----------------
#define ROWS 16384    // B*S
#define DIM  1024     // D
#define NEXP 8
#define DDIM 4096
#define KCAP 2048     // ROWS/NEXP

// ---------------- workspace layout (bytes) ----------------
#define WS_NORM    0ull                      // 33554432  (bf16 norm_x)
#define WS_G1      33554432ull               // 33554432  (bf16 gelu(cp fc1))
#define WS_YIN     67108864ull               // 33554432  (bf16 gathered rows)
#define WS_FCBUF   100663296ull              // 33554432  (bf16 4-expert weight buffer)
#define WS_H1      134217728ull              // 67108864  (bf16 [z<4][2048][4096])
#define WS_W1B     201326592ull              // 2097152   (bf16 cp_W1)
#define WS_S64     203423744ull              // 1048576   (f64 scores [n][row])
#define WS_S32     204472320ull              // 524288    (f32 scores [n][row])
#define WS_KIDX    204996608ull              // 65536
#define WS_MASK    205062144ull              // 131072    (u8 keep mask [row][n])
#define WS_PART    205193216ull              // 16384     (f32 per-block loss partials)
#define WS_NEEDED  205209600ull

// ================= LayerNorm + gate scores =================
__global__ __launch_bounds__(256)
void ln_score_k(const float* __restrict__ x, const float* __restrict__ lng,
                const float* __restrict__ lnb, const float* __restrict__ gw,
                unsigned short* __restrict__ normb, float* __restrict__ s32,
                double* __restrict__ s64)
{
  const int row = blockIdx.x;
  const int t = threadIdx.x, w = t >> 6, l = t & 63;
  const float* xr = x + (size_t)row * DIM;
  float4 v = ((const float4*)xr)[t];

  __shared__ float red[4];
  __shared__ float mu_s, inv_s;
  __shared__ double pd[4][8];

  float s = v.x + v.y + v.z + v.w;
  #pragma unroll
  for (int o = 32; o; o >>= 1) s += __shfl_xor(s, o);
  if (l == 0) red[w] = s;
  __syncthreads();
  if (t == 0) mu_s = (red[0] + red[1] + red[2] + red[3]) * (1.0f / DIM);
  __syncthreads();
  const float mu = mu_s;
  float d0 = v.x - mu, d1 = v.y - mu, d2 = v.z - mu, d3 = v.w - mu;
  float s2 = d0*d0 + d1*d1 + d2*d2 + d3*d3;
  #pragma unroll
  for (int o = 32; o; o >>= 1) s2 += __shfl_xor(s2, o);
  if (l == 0) red[w] = s2;
  __syncthreads();
  if (t == 0) {
    float var = (red[0] + red[1] + red[2] + red[3]) * (1.0f / DIM);
    inv_s = 1.0f / sqrtf(var + 1e-5f);
  }
  __syncthreads();
  const float inv = inv_s;

  float4 gv = ((const float4*)lng)[t];
  float4 bv = ((const float4*)lnb)[t];
  float n0 = d0 * inv * gv.x + bv.x;
  float n1 = d1 * inv * gv.y + bv.y;
  float n2 = d2 * inv * gv.z + bv.z;
  float n3 = d3 * inv * gv.w + bv.w;

  ushort4 nb;
  nb.x = f2bf(n0); nb.y = f2bf(n1); nb.z = f2bf(n2); nb.w = f2bf(n3);
  ((ushort4*)(normb + (size_t)row * DIM))[t] = nb;

  const int c0 = t * 4;
  double p[8];
  #pragma unroll
  for (int n = 0; n < 8; ++n) {
    float4 wv = *(const float4*)(gw + n * DIM + c0);
    p[n] = (double)n0 * wv.x + (double)n1 * wv.y + (double)n2 * wv.z + (double)n3 * wv.w;
  }
  #pragma unroll
  for (int n = 0; n < 8; ++n) {
    double q = p[n];
    #pragma unroll
    for (int o = 32; o; o >>= 1) q += __shfl_xor(q, o);
    if (l == 0) pd[w][n] = q;
  }
  __syncthreads();
  if (t < 8) {
    double d = pd[0][t] + pd[1][t] + pd[2][t] + pd[3][t];
    double sc = (tanh(d) + 1.0) * 0.5;
    s64[(size_t)t * ROWS + row] = sc;
    s32[(size_t)t * ROWS + row] = (float)sc;
  }
}

// ================= exact top-k per expert =================
// ping-pong single-barrier blockSum (saves one barrier + serial sum per round)
__global__ __launch_bounds__(1024)
void topk_k(const double* __restrict__ s64, int* __restrict__ kidx,
            unsigned char* __restrict__ mask)
{
  __shared__ int redc[2][16];
  __shared__ int cntr;
  const int n = blockIdx.x, t = threadIdx.x;
  const u64* keys = (const u64*)(s64 + (size_t)n * ROWS);
  u64 kk[16];
  #pragma unroll
  for (int i = 0; i < 16; ++i) kk[i] = keys[i * 1024 + t];

  int pp = 0;
  auto blockSum = [&](int local) -> int {
    #pragma unroll
    for (int o = 32; o; o >>= 1) local += __shfl_xor(local, o);
    if ((t & 63) == 0) redc[pp][t >> 6] = local;
    __syncthreads();
    int s = 0;
    #pragma unroll
    for (int i = 0; i < 16; ++i) s += redc[pp][i];
    pp ^= 1;
    return s;
  };

  // binary search for the k-th largest key value
  u64 lo = 0, hi = ~0ull;
  while (lo < hi) {
    u64 d = hi - lo;
    u64 mid = lo + (d >> 1) + (d & 1);
    int c = 0;
    #pragma unroll
    for (int i = 0; i < 16; ++i) c += (kk[i] >= mid);
    int tot = blockSum(c);
    if (tot >= KCAP) lo = mid; else hi = mid - 1;
  }
  const u64 kv = lo;
  int cg = 0;
  #pragma unroll
  for (int i = 0; i < 16; ++i) cg += (kk[i] > kv);
  const int m = blockSum(cg);
  const int need = KCAP - m;   // >=1

  // among keys == kv, keep the `need` smallest row indices (stable-sort tiebreak)
  int lo2 = 0, hi2 = ROWS;
  while (lo2 < hi2) {
    int mid = (lo2 + hi2) >> 1;
    int c2 = 0;
    #pragma unroll
    for (int i = 0; i < 16; ++i) c2 += (kk[i] == kv && (i * 1024 + t) < mid);
    int tot = blockSum(c2);
    if (tot >= need) hi2 = mid; else lo2 = mid + 1;
  }
  const int T = lo2;

  if (t == 0) cntr = 0;
  __syncthreads();
  #pragma unroll
  for (int i = 0; i < 16; ++i) {
    int r = i * 1024 + t;
    bool keep = (kk[i] > kv) || (kk[i] == kv && r < T);
    mask[(size_t)r * NEXP + n] = keep ? 1 : 0;
    if (keep) {
      int p = atomicAdd(&cntr, 1);
      kidx[n * KCAP + p] = r;
    }
  }
}

// ================= f32 -> bf16 convert =================
__global__ void cvt_k(const float* __restrict__ src, unsigned short* __restrict__ dst, int n4)
{
  int i = blockIdx.x * blockDim.x + threadIdx.x;
  int stride = gridDim.x * blockDim.x;
  for (; i < n4; i += stride) {
    float4 v = ((const float4*)src)[i];
    ushort4 o;
    o.x = f2bf(v.x); o.y = f2bf(v.y); o.z = f2bf(v.z); o.w = f2bf(v.w);
    ((ushort4*)dst)[i] = o;
  }
}

// ================= gather selected rows =================
__global__ __launch_bounds__(256)
void gather_k(const unsigned short* __restrict__ normb, const int* __restrict__ kidx,
              unsigned short* __restrict__ yin)
{
  int b = blockIdx.x;           // = n*2048 + j
  int row = kidx[b];
  const uint2* src = (const uint2*)(normb + (size_t)row * DIM);
  uint2* dst = (uint2*)(yin + (size_t)b * DIM);
  dst[threadIdx.x] = src[threadIdx.x];
}

// ================= 128x128 bf16 B^T GEMM, 2-phase dbuf =================
template<int EPI>
__global__ __launch_bounds__(256, 2)
void gemm_bt(const unsigned short* __restrict__ A, long strideAz, int lda,
             const unsigned short* __restrict__ B, long strideBz, int ldb,
             const float* __restrict__ bias, int strideBias,
             int K,
             unsigned short* __restrict__ outb, long strideOz, int ldo,
             float* __restrict__ outf, const int* __restrict__ kidx,
             const float* __restrict__ sc32, int n0)
{
  __shared__ __align__(16) char smem[32768];   // 2 x (A 8KB + B 8KB)
  const int t = threadIdx.x;
  const int w = t >> 6, l = t & 63;
  const int z = blockIdx.z;
  const int rowBase = blockIdx.y * 128;
  const int colBase = blockIdx.x * 128;
  const unsigned short* Ab = A + (long)z * strideAz + (long)rowBase * lda;
  const unsigned short* Bb = B + (long)z * strideBz + (long)colBase * ldb;
  const int srow = t >> 2, scol = (t & 3) * 8;
  const unsigned short* ga = Ab + (long)srow * lda + scol;
  const unsigned short* gb = Bb + (long)srow * ldb + scol;
  const int ldsW = w * 1024;     // per-wave chunk base (bytes)

  const int fr = l & 15, fq = l >> 4;
  const int wr = w >> 1, wc = w & 1;
  const int aoff = (wr * 64 + fr) * 64 + fq * 16;   // bytes into A tile
  const int boff = (wc * 64 + fr) * 64 + fq * 16;   // bytes into B tile

  f32x4 acc[4][4];
  #pragma unroll
  for (int mi = 0; mi < 4; ++mi)
    #pragma unroll
    for (int ni = 0; ni < 4; ++ni)
      acc[mi][ni] = (f32x4){0.f, 0.f, 0.f, 0.f};

  auto STAGE = [&](int buf, int k0) {
    char* s = smem + buf * 16384;
    gload16(ga + k0,                s + ldsW);
    gload16(ga + (long)64 * lda + k0, s + 4096 + ldsW);
    gload16(gb + k0,                s + 8192 + ldsW);
    gload16(gb + (long)64 * ldb + k0, s + 8192 + 4096 + ldsW);
  };

  STAGE(0, 0);
  __syncthreads();
  int cur = 0;
  for (int k0 = 0; k0 < K; k0 += 32) {
    if (k0 + 32 < K) STAGE(cur ^ 1, k0 + 32);
    const char* s = smem + cur * 16384;
    bf16x8 af[4], bfr[4];
    #pragma unroll
    for (int mi = 0; mi < 4; ++mi) af[mi] = *(const bf16x8*)(s + aoff + mi * 1024);
    #pragma unroll
    for (int ni = 0; ni < 4; ++ni) bfr[ni] = *(const bf16x8*)(s + 8192 + boff + ni * 1024);
    #pragma unroll
    for (int mi = 0; mi < 4; ++mi)
      #pragma unroll
      for (int ni = 0; ni < 4; ++ni)
        acc[mi][ni] = __builtin_amdgcn_mfma_f32_16x16x32_bf16(af[mi], bfr[ni], acc[mi][ni], 0, 0, 0);
    __syncthreads();
    cur ^= 1;
  }

  const int r0 = wr * 64 + fq * 4;
  const int c0 = wc * 64 + fr;
  if constexpr (EPI == 0) {
    #pragma unroll
    for (int mi = 0; mi < 4; ++mi) {
      #pragma unroll
      for (int ni = 0; ni < 4; ++ni) {
        int cg = colBase + c0 + ni * 16;
        float bv = bias[z * strideBias + cg];
        #pragma unroll
        for (int j = 0; j < 4; ++j) {
          int rg = rowBase + r0 + mi * 16 + j;
          float g = gelu_t(acc[mi][ni][j] + bv);
          outb[(long)z * strideOz + (long)rg * ldo + cg] = f2bf(g);
        }
      }
    }
  } else {
    const int n = n0 + z;
    const int* kk = kidx + n * KCAP;
    const float* ss = sc32 + (long)n * ROWS;
    #pragma unroll
    for (int mi = 0; mi < 4; ++mi) {
      #pragma unroll
      for (int j = 0; j < 4; ++j) {
        int rg = rowBase + r0 + mi * 16 + j;   // local row in [0,2048)
        int target = kk[rg];
        float sc = ss[target];
        #pragma unroll
        for (int ni = 0; ni < 4; ++ni) {
          int cg = colBase + c0 + ni * 16;
          float v = (acc[mi][ni][j] + bias[z * strideBias + cg]) * sc;
          atomicAdd(outf + (long)target * DIM + cg, v);
        }
      }
    }
  }
}

// ================= capacity logits + loss (block partials, no global atomic) =================
__global__ __launch_bounds__(256)
void cap_loss_k(const unsigned short* __restrict__ g1, const float* __restrict__ W2,
                const float* __restrict__ b2, const unsigned char* __restrict__ mask,
                float* __restrict__ partial)
{
  const int w = threadIdx.x >> 6, l = threadIdx.x & 63;
  const int row = blockIdx.x * 4 + w;
  const uint4* gr4 = (const uint4*)(g1 + (size_t)row * DIM) + l * 2;
  uint4 u0 = gr4[0], u1 = gr4[1];
  float gv[16];
  {
    unsigned uu[8] = {u0.x, u0.y, u0.z, u0.w, u1.x, u1.y, u1.z, u1.w};
    #pragma unroll
    for (int i = 0; i < 8; ++i) {
      gv[2 * i]     = bf2f((unsigned short)(uu[i] & 0xffff));
      gv[2 * i + 1] = bf2f((unsigned short)(uu[i] >> 16));
    }
  }
  float par[8];
  #pragma unroll
  for (int n = 0; n < 8; ++n) {
    const float* wp = W2 + n * DIM + l * 16;
    float s = 0.f;
    #pragma unroll
    for (int i = 0; i < 16; ++i) s += gv[i] * wp[i];
    par[n] = s;
  }
  #pragma unroll
  for (int n = 0; n < 8; ++n) {
    float p = par[n];
    #pragma unroll
    for (int o = 32; o; o >>= 1) p += __shfl_xor(p, o);
    par[n] = p;
  }
  __shared__ float wred[4];
  if (l == 0) {
    float lsum = 0.f;
    #pragma unroll
    for (int n = 0; n < 8; ++n) {
      float lg = par[n] + b2[n];
      float sp = fmaxf(lg, 0.f) + log1pf(expf(-fabsf(lg)));
      lsum += sp - lg * (float)mask[(size_t)row * NEXP + n];
    }
    wred[w] = lsum;
  }
  __syncthreads();
  if (threadIdx.x == 0)
    partial[blockIdx.x] = (wred[0] + wred[1] + wred[2] + wred[3]) * (1.0f / (ROWS * (float)NEXP));
}

// ================= final loss reduce =================
__global__ __launch_bounds__(256)
void loss_reduce_k(const float* __restrict__ partial, float* __restrict__ o, int pos, int n)
{
  const int t = threadIdx.x, w = t >> 6, l = t & 63;
  float s = 0.f;
  for (int i = t; i < n; i += 256) s += partial[i];
  #pragma unroll
  for (int off = 32; off; off >>= 1) s += __shfl_xor(s, off);
  __shared__ float r[4];
  if (l == 0) r[w] = s;
  __syncthreads();
  if (t == 0) o[pos] = r[0] + r[1] + r[2] + r[3];
}

// ================= launch =================
extern "C" void kernel_launch(void* const* d_in, const int* in_sizes, int n_in,
                              void* d_out, int out_size, void* d_ws, size_t ws_size,
                              hipStream_t stream)
{
  if (ws_size < WS_NEEDED) return;

  const float* x     = (const float*)d_in[0];
  const float* ln_g  = (const float*)d_in[1];
  const float* ln_b  = (const float*)d_in[2];
  const float* gateW = (const float*)d_in[3];
  const float* cpW1  = (const float*)d_in[4];
  const float* cpb1  = (const float*)d_in[5];
  const float* cpW2  = (const float*)d_in[6];
  const float* cpb2  = (const float*)d_in[7];
  const float* fc1s  = (const float*)d_in[8];
  const float* b1s   = (const float*)d_in[9];
  const float* fc2s  = (const float*)d_in[10];
  const float* b2s   = (const float*)d_in[11];

  char* ws = (char*)d_ws;
  unsigned short* normb = (unsigned short*)(ws + WS_NORM);
  unsigned short* g1    = (unsigned short*)(ws + WS_G1);
  unsigned short* yin   = (unsigned short*)(ws + WS_YIN);
  unsigned short* fcbuf = (unsigned short*)(ws + WS_FCBUF);
  unsigned short* h1    = (unsigned short*)(ws + WS_H1);
  unsigned short* w1b   = (unsigned short*)(ws + WS_W1B);
  double*  s64 = (double*)(ws + WS_S64);
  float*   s32 = (float*)(ws + WS_S32);
  int*     kidx = (int*)(ws + WS_KIDX);
  unsigned char* mask = (unsigned char*)(ws + WS_MASK);
  float*   part = (float*)(ws + WS_PART);
  float*   out = (float*)d_out;

  hipMemcpyAsync(out, x, (size_t)ROWS * DIM * sizeof(float), hipMemcpyDeviceToDevice, stream);

  ln_score_k<<<ROWS, 256, 0, stream>>>(x, ln_g, ln_b, gateW, normb, s32, s64);
  topk_k<<<NEXP, 1024, 0, stream>>>(s64, kidx, mask);

  // capacity predictor
  cvt_k<<<2048, 256, 0, stream>>>(cpW1, w1b, DIM * DIM / 4);
  gemm_bt<0><<<dim3(DIM / 128, ROWS / 128, 1), 256, 0, stream>>>(
      normb, 0, DIM, w1b, 0, DIM, cpb1, 0, DIM,
      g1, 0, DIM, nullptr, nullptr, nullptr, 0);
  cap_loss_k<<<ROWS / 4, 256, 0, stream>>>(g1, cpW2, cpb2, mask, part);
  loss_reduce_k<<<1, 256, 0, stream>>>(part, out, out_size - 1, ROWS / 4);

  // expert path
  gather_k<<<NEXP * KCAP, 256, 0, stream>>>(normb, kidx, yin);
  for (int h = 0; h < 2; ++h) {
    cvt_k<<<4096, 256, 0, stream>>>(fc1s + (size_t)h * 4 * DDIM * DIM, fcbuf, 4 * DDIM * DIM / 4);
    gemm_bt<0><<<dim3(DDIM / 128, KCAP / 128, 4), 256, 0, stream>>>(
        yin + (size_t)h * 4 * KCAP * DIM, (long)KCAP * DIM, DIM,
        fcbuf, (long)DDIM * DIM, DIM,
        b1s + h * 4 * DDIM, DDIM, DIM,
        h1, (long)KCAP * DDIM, DDIM, nullptr, nullptr, nullptr, 0);
    cvt_k<<<4096, 256, 0, stream>>>(fc2s + (size_t)h * 4 * DIM * DDIM, fcbuf, 4 * DIM * DDIM / 4);
    gemm_bt<1><<<dim3(DIM / 128, KCAP / 128, 4), 256, 0, stream>>>(
        h1, (long)KCAP * DDIM, DDIM,
        fcbuf, (long)DIM * DDIM, DDIM,
        b2s + h * 4 * DIM, DIM, DDIM,
        nullptr, 0, 0, out, kidx, s32, h * 4);
  }
}